// Round 1
// baseline (1372.041 us; speedup 1.0000x reference)
//
#include <hip/hip_runtime.h>

#define N_NODES 100000
#define N_EDGES 1600000
#define D 128

// ---------------- degree / normalization ----------------

__global__ void deg_kernel(const int* __restrict__ dst, float* __restrict__ deg) {
    int i = blockIdx.x * blockDim.x + threadIdx.x;
    if (i < N_EDGES) atomicAdd(&deg[dst[i]], 1.0f);
}

__global__ void dinv_kernel(float* __restrict__ deg) {
    int i = blockIdx.x * blockDim.x + threadIdx.x;
    // +1.0f accounts for the self-loop; deg >= 1 always, so no max() needed.
    if (i < N_NODES) deg[i] = rsqrtf(deg[i] + 1.0f);
}

// ---------------- layer 1 GEMM: xw1 = feature @ W1  [N,128]x[128,128] ----------------
// Block = 256 threads = 2 rows x 128 cols. Feature rows staged in LDS;
// W1 rows are broadcast-read (64 KB, L1/L2 resident).

__global__ __launch_bounds__(256) void gemm1_kernel(const float* __restrict__ x,
                                                    const float* __restrict__ W,
                                                    float* __restrict__ xw) {
    __shared__ float xs[2][D];
    const int r = threadIdx.x >> 7;     // 0..1
    const int c = threadIdx.x & 127;    // 0..127
    const int row = blockIdx.x * 2 + r; // N_NODES even -> never OOB
    xs[r][c] = x[row * D + c];
    __syncthreads();
    float acc = 0.0f;
#pragma unroll 8
    for (int k = 0; k < D; ++k) {
        acc += xs[r][k] * W[k * D + c];
    }
    xw[row * D + c] = acc;
}

// ---------------- layer 1 scatter: hacc[dst] += xw1[src] * norm ----------------
// 4 edges per 512-thread block; 128 channels per edge (one thread each).
// Self-loops handled separately (fused into relu_kernel) -> no atomics for them.

__global__ __launch_bounds__(512) void scatter1_kernel(const int* __restrict__ src,
                                                       const int* __restrict__ dst,
                                                       const float* __restrict__ dinv,
                                                       const float* __restrict__ xw,
                                                       float* __restrict__ hacc) {
    const int e = blockIdx.x * 4 + (threadIdx.x >> 7);
    const int c = threadIdx.x & 127;
    const int s = src[e];
    const int d = dst[e];
    const float nrm = dinv[s] * dinv[d];
    atomicAdd(&hacc[d * D + c], xw[s * D + c] * nrm);
}

// ---------------- layer 1 epilogue: self-loop + bias + ReLU (in place) ----------------

__global__ void relu_kernel(float* __restrict__ hacc,
                            const float* __restrict__ xw,
                            const float* __restrict__ dinv,
                            const float* __restrict__ b) {
    const int i = blockIdx.x * blockDim.x + threadIdx.x;  // over N*D, exact multiple of 256
    const int node = i >> 7;
    const int c = i & 127;
    const float di = dinv[node];
    const float v = hacc[i] + xw[i] * (di * di) + b[c];
    hacc[i] = fmaxf(v, 0.0f);
}

// ---------------- layer 2 GEMM: xw2 = h @ W2  [N,128]x[128,3] ----------------
// One wave per row; each lane covers 2 of the 128 K-elements; shuffle-reduce 3 outputs.

__global__ __launch_bounds__(256) void gemm2_kernel(const float* __restrict__ h,
                                                    const float* __restrict__ W2,
                                                    float* __restrict__ xw2) {
    const int lane = threadIdx.x & 63;
    const int row = blockIdx.x * 4 + (threadIdx.x >> 6);  // N_NODES % 4 == 0
    const float x0 = h[row * D + lane];
    const float x1 = h[row * D + 64 + lane];
    float a0 = x0 * W2[lane * 3 + 0] + x1 * W2[(lane + 64) * 3 + 0];
    float a1 = x0 * W2[lane * 3 + 1] + x1 * W2[(lane + 64) * 3 + 1];
    float a2 = x0 * W2[lane * 3 + 2] + x1 * W2[(lane + 64) * 3 + 2];
#pragma unroll
    for (int off = 32; off; off >>= 1) {
        a0 += __shfl_xor(a0, off);
        a1 += __shfl_xor(a1, off);
        a2 += __shfl_xor(a2, off);
    }
    if (lane == 0) {
        xw2[row * 3 + 0] = a0;
        xw2[row * 3 + 1] = a1;
        xw2[row * 3 + 2] = a2;
    }
}

// ---------------- layer 2 scatter: out[dst] += xw2[src] * norm ----------------

__global__ void scatter2_kernel(const int* __restrict__ src,
                                const int* __restrict__ dst,
                                const float* __restrict__ dinv,
                                const float* __restrict__ xw2,
                                float* __restrict__ out) {
    const int e = blockIdx.x * blockDim.x + threadIdx.x;
    if (e >= N_EDGES) return;
    const int s = src[e];
    const int d = dst[e];
    const float nrm = dinv[s] * dinv[d];
    atomicAdd(&out[d * 3 + 0], xw2[s * 3 + 0] * nrm);
    atomicAdd(&out[d * 3 + 1], xw2[s * 3 + 1] * nrm);
    atomicAdd(&out[d * 3 + 2], xw2[s * 3 + 2] * nrm);
}

// ---------------- layer 2 epilogue: self-loop + bias (in place) ----------------

__global__ void final_kernel(float* __restrict__ out,
                             const float* __restrict__ xw2,
                             const float* __restrict__ dinv,
                             const float* __restrict__ b2) {
    const int i = blockIdx.x * blockDim.x + threadIdx.x;
    if (i >= N_NODES) return;
    const float di = dinv[i];
    const float d2 = di * di;
    out[i * 3 + 0] += xw2[i * 3 + 0] * d2 + b2[0];
    out[i * 3 + 1] += xw2[i * 3 + 1] * d2 + b2[1];
    out[i * 3 + 2] += xw2[i * 3 + 2] * d2 + b2[2];
}

// ---------------- launch ----------------

extern "C" void kernel_launch(void* const* d_in, const int* in_sizes, int n_in,
                              void* d_out, int out_size, void* d_ws, size_t ws_size,
                              hipStream_t stream) {
    const float* feature = (const float*)d_in[0];
    const int* edge_index = (const int*)d_in[1];
    const int* src = edge_index;             // edge_index[0, :]
    const int* dst = edge_index + N_EDGES;   // edge_index[1, :]
    // d_in[2] = edge_type (unused at inference)
    const float* W1 = (const float*)d_in[3];
    const float* b1 = (const float*)d_in[4];
    const float* W2 = (const float*)d_in[5];
    const float* b2 = (const float*)d_in[6];
    float* out = (float*)d_out;

    char* ws = (char*)d_ws;
    float* dinv = (float*)ws;                               // N floats (0.4 MB)
    float* xw1  = (float*)(ws + (1 << 20));                 // N*D floats (51.2 MB)
    float* hacc = xw1 + (size_t)N_NODES * D;                // N*D floats (51.2 MB)
    float* xw2  = hacc + (size_t)N_NODES * D;               // N*3 floats (1.2 MB)

    // Zero the accumulators (ws/out are poisoned 0xAA before every timed call).
    hipMemsetAsync(dinv, 0, N_NODES * sizeof(float), stream);
    hipMemsetAsync(hacc, 0, (size_t)N_NODES * D * sizeof(float), stream);
    hipMemsetAsync(out, 0, (size_t)N_NODES * 3 * sizeof(float), stream);

    deg_kernel<<<(N_EDGES + 255) / 256, 256, 0, stream>>>(dst, dinv);
    dinv_kernel<<<(N_NODES + 255) / 256, 256, 0, stream>>>(dinv);
    gemm1_kernel<<<N_NODES / 2, 256, 0, stream>>>(feature, W1, xw1);
    scatter1_kernel<<<N_EDGES / 4, 512, 0, stream>>>(src, dst, dinv, xw1, hacc);
    relu_kernel<<<(N_NODES * D) / 256, 256, 0, stream>>>(hacc, xw1, dinv, b1);
    gemm2_kernel<<<N_NODES / 4, 256, 0, stream>>>(hacc, W2, xw2);
    scatter2_kernel<<<(N_EDGES + 255) / 256, 256, 0, stream>>>(src, dst, dinv, xw2, out);
    final_kernel<<<(N_NODES + 255) / 256, 256, 0, stream>>>(out, xw2, dinv, b2);
}

// Round 2
// 730.646 us; speedup vs baseline: 1.8778x; 1.8778x over previous
//
#include <hip/hip_runtime.h>

#define N_NODES 100000
#define N_EDGES 1600000
#define D 128

// ---------------- degree histogram (int) ----------------

__global__ void deg_kernel(const int* __restrict__ dst, int* __restrict__ cnt) {
    int i = blockIdx.x * blockDim.x + threadIdx.x;
    if (i < N_EDGES) atomicAdd(&cnt[dst[i]], 1);
}

__global__ void dinv_kernel(const int* __restrict__ cnt, float* __restrict__ dinv) {
    int i = blockIdx.x * blockDim.x + threadIdx.x;
    // +1 accounts for the self-loop; deg >= 1 always.
    if (i < N_NODES) dinv[i] = rsqrtf((float)cnt[i] + 1.0f);
}

// ---------------- exclusive scan over cnt -> row_ptr[N+1] (single block) ----------------

__global__ __launch_bounds__(1024) void scan_kernel(const int* __restrict__ cnt,
                                                    int* __restrict__ row_ptr) {
    __shared__ int sums[1024];
    const int t = threadIdx.x;
    const int CH = (N_NODES + 1023) / 1024;  // 98
    const int base = t * CH;
    int local = 0;
    for (int i = 0; i < CH; ++i) {
        int idx = base + i;
        if (idx < N_NODES) local += cnt[idx];
    }
    sums[t] = local;
    __syncthreads();
    // Hillis-Steele inclusive scan
    for (int off = 1; off < 1024; off <<= 1) {
        int v = (t >= off) ? sums[t - off] : 0;
        __syncthreads();
        sums[t] += v;
        __syncthreads();
    }
    int prefix = (t == 0) ? 0 : sums[t - 1];
    for (int i = 0; i < CH; ++i) {
        int idx = base + i;
        if (idx < N_NODES) {
            row_ptr[idx] = prefix;
            prefix += cnt[idx];
        }
    }
    if (t == 1023) row_ptr[N_NODES] = prefix;  // = N_EDGES
}

// ---------------- fill CSR: esrc sorted by dst ----------------

__global__ void fill_kernel(const int* __restrict__ src, const int* __restrict__ dst,
                            const int* __restrict__ row_ptr, int* __restrict__ cursor,
                            int* __restrict__ esrc) {
    int e = blockIdx.x * blockDim.x + threadIdx.x;
    if (e >= N_EDGES) return;
    int d = dst[e];
    int pos = row_ptr[d] + atomicAdd(&cursor[d], 1);
    esrc[pos] = src[e];
}

// ---------------- layer 1 GEMM: xw1 = feature @ W1, W1 fully in LDS ----------------
// Block = 256 threads, 16 rows. Thread handles rows {r, r+8} x cols [c0, c0+4).

__global__ __launch_bounds__(256) void gemm1_kernel(const float* __restrict__ x,
                                                    const float* __restrict__ W,
                                                    float* __restrict__ xw) {
    __shared__ float ws[D * D];   // 64 KB
    __shared__ float xs[16][D];   // 8 KB
    const int tid = threadIdx.x;
    const float4* W4 = (const float4*)W;
    float4* ws4 = (float4*)ws;
#pragma unroll
    for (int i = 0; i < 16; ++i) ws4[tid + i * 256] = W4[tid + i * 256];  // 4096 float4
    const int row0 = blockIdx.x * 16;  // N_NODES % 16 == 0
    const float4* x4 = (const float4*)(x + (size_t)row0 * D);
    float4* xs4 = (float4*)xs;
    xs4[tid] = x4[tid];
    xs4[tid + 256] = x4[tid + 256];
    __syncthreads();
    const int r = tid >> 5;          // 0..7
    const int c0 = (tid & 31) * 4;   // conflict-free float4 column group
    float acc0[4] = {0, 0, 0, 0}, acc1[4] = {0, 0, 0, 0};
#pragma unroll 8
    for (int k = 0; k < D; ++k) {
        const float4 wv = *(const float4*)&ws[k * D + c0];
        const float xv0 = xs[r][k];
        const float xv1 = xs[r + 8][k];
        acc0[0] += xv0 * wv.x; acc0[1] += xv0 * wv.y;
        acc0[2] += xv0 * wv.z; acc0[3] += xv0 * wv.w;
        acc1[0] += xv1 * wv.x; acc1[1] += xv1 * wv.y;
        acc1[2] += xv1 * wv.z; acc1[3] += xv1 * wv.w;
    }
    *(float4*)&xw[(size_t)(row0 + r) * D + c0] = *(float4*)acc0;
    *(float4*)&xw[(size_t)(row0 + r + 8) * D + c0] = *(float4*)acc1;
}

// ---------------- layer 1 gather: h[n] = relu((sum_e xw[s]*dinv[s] + xw[n]*dinv[n])*dinv[n] + b) ----------------
// 2 nodes per 256-thread block; thread c accumulates channel c in a register. No atomics.

__global__ __launch_bounds__(256) void gather1_kernel(const int* __restrict__ row_ptr,
                                                      const int* __restrict__ esrc,
                                                      const float* __restrict__ dinv,
                                                      const float* __restrict__ xw,
                                                      const float* __restrict__ b,
                                                      float* __restrict__ h) {
    const int n = blockIdx.x * 2 + (threadIdx.x >> 7);  // N_NODES even
    const int c = threadIdx.x & 127;
    const int beg = row_ptr[n], end = row_ptr[n + 1];
    float acc = 0.0f;
    int j = beg;
    for (; j + 1 < end; j += 2) {  // 2 independent load chains for ILP
        const int s0 = esrc[j];
        const int s1 = esrc[j + 1];
        const float d0 = dinv[s0];
        const float d1 = dinv[s1];
        acc += xw[(size_t)s0 * D + c] * d0;
        acc += xw[(size_t)s1 * D + c] * d1;
    }
    if (j < end) {
        const int s = esrc[j];
        acc += xw[(size_t)s * D + c] * dinv[s];
    }
    const float dn = dinv[n];
    acc = (acc + xw[(size_t)n * D + c] * dn) * dn + b[c];
    h[(size_t)n * D + c] = fmaxf(acc, 0.0f);
}

// ---------------- layer 2 GEMM: xw2 = h @ W2  [N,128]x[128,3] ----------------

__global__ __launch_bounds__(256) void gemm2_kernel(const float* __restrict__ h,
                                                    const float* __restrict__ W2,
                                                    float* __restrict__ xw2) {
    const int lane = threadIdx.x & 63;
    const int row = blockIdx.x * 4 + (threadIdx.x >> 6);  // N_NODES % 4 == 0
    const float x0 = h[(size_t)row * D + lane];
    const float x1 = h[(size_t)row * D + 64 + lane];
    float a0 = x0 * W2[lane * 3 + 0] + x1 * W2[(lane + 64) * 3 + 0];
    float a1 = x0 * W2[lane * 3 + 1] + x1 * W2[(lane + 64) * 3 + 1];
    float a2 = x0 * W2[lane * 3 + 2] + x1 * W2[(lane + 64) * 3 + 2];
#pragma unroll
    for (int off = 32; off; off >>= 1) {
        a0 += __shfl_xor(a0, off);
        a1 += __shfl_xor(a1, off);
        a2 += __shfl_xor(a2, off);
    }
    if (lane == 0) {
        xw2[row * 3 + 0] = a0;
        xw2[row * 3 + 1] = a1;
        xw2[row * 3 + 2] = a2;
    }
}

// ---------------- layer 2 gather: wave per node, lanes over edges ----------------

__global__ __launch_bounds__(256) void gather2_kernel(const int* __restrict__ row_ptr,
                                                      const int* __restrict__ esrc,
                                                      const float* __restrict__ dinv,
                                                      const float* __restrict__ xw2,
                                                      const float* __restrict__ b2,
                                                      float* __restrict__ out) {
    const int node = blockIdx.x * 4 + (threadIdx.x >> 6);  // N_NODES % 4 == 0
    const int lane = threadIdx.x & 63;
    const int beg = row_ptr[node], end = row_ptr[node + 1];
    float a0 = 0.0f, a1 = 0.0f, a2 = 0.0f;
    for (int j = beg + lane; j < end; j += 64) {
        const int s = esrc[j];
        const float ds = dinv[s];
        a0 += xw2[s * 3 + 0] * ds;
        a1 += xw2[s * 3 + 1] * ds;
        a2 += xw2[s * 3 + 2] * ds;
    }
#pragma unroll
    for (int off = 32; off; off >>= 1) {
        a0 += __shfl_xor(a0, off);
        a1 += __shfl_xor(a1, off);
        a2 += __shfl_xor(a2, off);
    }
    if (lane == 0) {
        const float dn = dinv[node];
        out[node * 3 + 0] = (a0 + xw2[node * 3 + 0] * dn) * dn + b2[0];
        out[node * 3 + 1] = (a1 + xw2[node * 3 + 1] * dn) * dn + b2[1];
        out[node * 3 + 2] = (a2 + xw2[node * 3 + 2] * dn) * dn + b2[2];
    }
}

// ---------------- launch ----------------

extern "C" void kernel_launch(void* const* d_in, const int* in_sizes, int n_in,
                              void* d_out, int out_size, void* d_ws, size_t ws_size,
                              hipStream_t stream) {
    const float* feature = (const float*)d_in[0];
    const int* edge_index = (const int*)d_in[1];
    const int* src = edge_index;             // edge_index[0, :]
    const int* dst = edge_index + N_EDGES;   // edge_index[1, :]
    const float* W1 = (const float*)d_in[3];
    const float* b1 = (const float*)d_in[4];
    const float* W2 = (const float*)d_in[5];
    const float* b2 = (const float*)d_in[6];
    float* out = (float*)d_out;

    const size_t ND = (size_t)N_NODES * D;
    float* xw1     = (float*)d_ws;                 // 51.2 MB
    float* h       = xw1 + ND;                     // 51.2 MB
    float* xw2     = h + ND;                       // 1.2 MB
    float* dinv    = xw2 + (size_t)N_NODES * 3;    // 0.4 MB
    int*   cnt     = (int*)(dinv + N_NODES);       // 0.4 MB (reused as cursor)
    int*   row_ptr = cnt + N_NODES;                // 0.4 MB
    int*   esrc    = row_ptr + (N_NODES + 1);      // 6.4 MB

    // CSR build (by dst)
    hipMemsetAsync(cnt, 0, N_NODES * sizeof(int), stream);
    deg_kernel<<<(N_EDGES + 255) / 256, 256, 0, stream>>>(dst, cnt);
    dinv_kernel<<<(N_NODES + 255) / 256, 256, 0, stream>>>(cnt, dinv);
    scan_kernel<<<1, 1024, 0, stream>>>(cnt, row_ptr);
    hipMemsetAsync(cnt, 0, N_NODES * sizeof(int), stream);  // reuse as cursor
    fill_kernel<<<(N_EDGES + 255) / 256, 256, 0, stream>>>(src, dst, row_ptr, cnt, esrc);

    // layer 1
    gemm1_kernel<<<N_NODES / 16, 256, 0, stream>>>(feature, W1, xw1);
    gather1_kernel<<<N_NODES / 2, 256, 0, stream>>>(row_ptr, esrc, dinv, xw1, b1, h);

    // layer 2
    gemm2_kernel<<<N_NODES / 4, 256, 0, stream>>>(h, W2, xw2);
    gather2_kernel<<<N_NODES / 4, 256, 0, stream>>>(row_ptr, esrc, dinv, xw2, b2, out);
}

// Round 5
// 444.816 us; speedup vs baseline: 3.0845x; 1.6426x over previous
//
#include <hip/hip_runtime.h>

#define N_NODES 100000
#define N_EDGES 1600000
#define D 128
#define NB_SCAN 391  // ceil(100000/256)

// ---------------- degree histogram (int) ----------------

__global__ void deg_kernel(const int* __restrict__ dst, int* __restrict__ cnt) {
    int i = blockIdx.x * blockDim.x + threadIdx.x;
    if (i < N_EDGES) atomicAdd(&cnt[dst[i]], 1);
}

__global__ void dinv_kernel(const int* __restrict__ cnt, float* __restrict__ dinv) {
    int i = blockIdx.x * blockDim.x + threadIdx.x;
    // +1 accounts for the self-loop; deg >= 1 always.
    if (i < N_NODES) dinv[i] = rsqrtf((float)cnt[i] + 1.0f);
}

// ---------------- hierarchical exclusive scan: cnt[100000] -> row_ptr[100001] ----------------

__global__ __launch_bounds__(256) void scan1_kernel(const int* __restrict__ cnt,
                                                    int* __restrict__ bsum) {
    __shared__ int s[256];
    const int t = threadIdx.x;
    const int idx = blockIdx.x * 256 + t;
    s[t] = (idx < N_NODES) ? cnt[idx] : 0;
    __syncthreads();
    for (int off = 128; off; off >>= 1) {
        if (t < off) s[t] += s[t + off];
        __syncthreads();
    }
    if (t == 0) bsum[blockIdx.x] = s[0];
}

__global__ __launch_bounds__(512) void scan2_kernel(const int* __restrict__ bsum,
                                                    int* __restrict__ boff,
                                                    int* __restrict__ row_ptr) {
    __shared__ int s[512];
    const int t = threadIdx.x;
    const int v = (t < NB_SCAN) ? bsum[t] : 0;
    s[t] = v;
    __syncthreads();
    for (int off = 1; off < 512; off <<= 1) {
        int u = (t >= off) ? s[t - off] : 0;
        __syncthreads();
        s[t] += u;
        __syncthreads();
    }
    if (t < NB_SCAN) boff[t] = s[t] - v;  // exclusive block offset
    if (t == 0) row_ptr[N_NODES] = N_EDGES;
}

__global__ __launch_bounds__(256) void scan3_kernel(const int* __restrict__ cnt,
                                                    const int* __restrict__ boff,
                                                    int* __restrict__ row_ptr) {
    __shared__ int s[256];
    const int t = threadIdx.x;
    const int idx = blockIdx.x * 256 + t;
    const int v = (idx < N_NODES) ? cnt[idx] : 0;
    s[t] = v;
    __syncthreads();
    for (int off = 1; off < 256; off <<= 1) {
        int u = (t >= off) ? s[t - off] : 0;
        __syncthreads();
        s[t] += u;
        __syncthreads();
    }
    if (idx < N_NODES) row_ptr[idx] = boff[blockIdx.x] + s[t] - v;  // exclusive
}

// ---------------- fill CSR (esrc grouped by dst); cnt counts DOWN to avoid re-zeroing ----------------

__global__ void fill_kernel(const int* __restrict__ src, const int* __restrict__ dst,
                            const int* __restrict__ row_ptr, int* __restrict__ cnt,
                            int* __restrict__ esrc) {
    int e = blockIdx.x * blockDim.x + threadIdx.x;
    if (e >= N_EDGES) return;
    int d = dst[e];
    int pos = row_ptr[d] + atomicSub(&cnt[d], 1) - 1;  // unique slot in [row_ptr[d], row_ptr[d]+deg)
    esrc[pos] = src[e];
}

// ---------------- layer 1 GEMM: xw1 = feature @ W1, W1 fully in LDS ----------------

__global__ __launch_bounds__(256) void gemm1_kernel(const float* __restrict__ x,
                                                    const float* __restrict__ W,
                                                    float* __restrict__ xw) {
    __shared__ float ws[D * D];   // 64 KB
    __shared__ float xs[16][D];   // 8 KB
    const int tid = threadIdx.x;
    const float4* W4 = (const float4*)W;
    float4* ws4 = (float4*)ws;
#pragma unroll
    for (int i = 0; i < 16; ++i) ws4[tid + i * 256] = W4[tid + i * 256];
    const int row0 = blockIdx.x * 16;  // N_NODES % 16 == 0
    const float4* x4 = (const float4*)(x + (size_t)row0 * D);
    float4* xs4 = (float4*)xs;
    xs4[tid] = x4[tid];
    xs4[tid + 256] = x4[tid + 256];
    __syncthreads();
    const int r = tid >> 5;          // 0..7
    const int c0 = (tid & 31) * 4;
    float acc0[4] = {0, 0, 0, 0}, acc1[4] = {0, 0, 0, 0};
#pragma unroll 8
    for (int k = 0; k < D; ++k) {
        const float4 wv = *(const float4*)&ws[k * D + c0];
        const float xv0 = xs[r][k];
        const float xv1 = xs[r + 8][k];
        acc0[0] += xv0 * wv.x; acc0[1] += xv0 * wv.y;
        acc0[2] += xv0 * wv.z; acc0[3] += xv0 * wv.w;
        acc1[0] += xv1 * wv.x; acc1[1] += xv1 * wv.y;
        acc1[2] += xv1 * wv.z; acc1[3] += xv1 * wv.w;
    }
    *(float4*)&xw[(size_t)(row0 + r) * D + c0] = *(float4*)acc0;
    *(float4*)&xw[(size_t)(row0 + r + 8) * D + c0] = *(float4*)acc1;
}

// ---------------- layer 1 gather + fused layer 2 GEMM ----------------
// 8 nodes per 256-thread block; 32 threads per node, float4 per thread (4 channels).
// h is computed in registers, multiplied by W2 (128x3) and shuffle-reduced -> xw2.
// h never touches memory.

__global__ __launch_bounds__(256) void gather1_kernel(const int* __restrict__ row_ptr,
                                                      const int* __restrict__ esrc,
                                                      const float* __restrict__ dinv,
                                                      const float* __restrict__ xw,
                                                      const float* __restrict__ b1,
                                                      const float* __restrict__ W2,
                                                      float* __restrict__ xw2) {
    const int t = threadIdx.x;
    const int n = blockIdx.x * 8 + (t >> 5);  // N_NODES % 8 == 0
    const int g = t & 31;                      // 4-channel group within the row
    const float4* xw4 = (const float4*)xw;
    const int beg = row_ptr[n], end = row_ptr[n + 1];
    float ax = 0.f, ay = 0.f, az = 0.f, aw = 0.f;
    int j = beg;
    for (; j + 1 < end; j += 2) {  // two independent 16B load chains
        const int s0 = esrc[j];
        const int s1 = esrc[j + 1];
        const float d0 = dinv[s0];
        const float d1 = dinv[s1];
        const float4 v0 = xw4[(size_t)s0 * 32 + g];
        const float4 v1 = xw4[(size_t)s1 * 32 + g];
        ax += v0.x * d0 + v1.x * d1;
        ay += v0.y * d0 + v1.y * d1;
        az += v0.z * d0 + v1.z * d1;
        aw += v0.w * d0 + v1.w * d1;
    }
    if (j < end) {
        const int s = esrc[j];
        const float ds = dinv[s];
        const float4 v = xw4[(size_t)s * 32 + g];
        ax += v.x * ds; ay += v.y * ds; az += v.z * ds; aw += v.w * ds;
    }
    const float dn = dinv[n];
    const float4 vn = xw4[(size_t)n * 32 + g];
    const float4 bb = ((const float4*)b1)[g];
    const float h0 = fmaxf((ax + vn.x * dn) * dn + bb.x, 0.f);
    const float h1 = fmaxf((ay + vn.y * dn) * dn + bb.y, 0.f);
    const float h2 = fmaxf((az + vn.z * dn) * dn + bb.z, 0.f);
    const float h3 = fmaxf((aw + vn.w * dn) * dn + bb.w, 0.f);
    // fused gemm2: channels c = 4g..4g+3; W2 is [128][3], 1.5 KB (L1-resident)
    const int c = g * 4;
    float a0 = h0 * W2[c * 3 + 0] + h1 * W2[(c + 1) * 3 + 0] + h2 * W2[(c + 2) * 3 + 0] + h3 * W2[(c + 3) * 3 + 0];
    float a1 = h0 * W2[c * 3 + 1] + h1 * W2[(c + 1) * 3 + 1] + h2 * W2[(c + 2) * 3 + 1] + h3 * W2[(c + 3) * 3 + 1];
    float a2 = h0 * W2[c * 3 + 2] + h1 * W2[(c + 1) * 3 + 2] + h2 * W2[(c + 2) * 3 + 2] + h3 * W2[(c + 3) * 3 + 2];
#pragma unroll
    for (int off = 16; off; off >>= 1) {  // reduce within the 32-lane group
        a0 += __shfl_xor(a0, off);
        a1 += __shfl_xor(a1, off);
        a2 += __shfl_xor(a2, off);
    }
    if (g == 0) {
        xw2[n * 3 + 0] = a0;
        xw2[n * 3 + 1] = a1;
        xw2[n * 3 + 2] = a2;
    }
}

// ---------------- layer 2 gather: 4 lanes per node ----------------

__global__ __launch_bounds__(256) void gather2_kernel(const int* __restrict__ row_ptr,
                                                      const int* __restrict__ esrc,
                                                      const float* __restrict__ dinv,
                                                      const float* __restrict__ xw2,
                                                      const float* __restrict__ b2,
                                                      float* __restrict__ out) {
    const int t = threadIdx.x;
    const int node = blockIdx.x * 64 + (t >> 2);
    if (node >= N_NODES) return;
    const int sub = t & 3;
    const int beg = row_ptr[node], end = row_ptr[node + 1];
    float a0 = 0.f, a1 = 0.f, a2 = 0.f;
    for (int j = beg + sub; j < end; j += 4) {
        const int s = esrc[j];
        const float ds = dinv[s];
        a0 += xw2[s * 3 + 0] * ds;
        a1 += xw2[s * 3 + 1] * ds;
        a2 += xw2[s * 3 + 2] * ds;
    }
    a0 += __shfl_xor(a0, 1); a0 += __shfl_xor(a0, 2);
    a1 += __shfl_xor(a1, 1); a1 += __shfl_xor(a1, 2);
    a2 += __shfl_xor(a2, 1); a2 += __shfl_xor(a2, 2);
    if (sub == 0) {
        const float dn = dinv[node];
        out[node * 3 + 0] = (a0 + xw2[node * 3 + 0] * dn) * dn + b2[0];
        out[node * 3 + 1] = (a1 + xw2[node * 3 + 1] * dn) * dn + b2[1];
        out[node * 3 + 2] = (a2 + xw2[node * 3 + 2] * dn) * dn + b2[2];
    }
}

// ---------------- launch ----------------

extern "C" void kernel_launch(void* const* d_in, const int* in_sizes, int n_in,
                              void* d_out, int out_size, void* d_ws, size_t ws_size,
                              hipStream_t stream) {
    const float* feature = (const float*)d_in[0];
    const int* edge_index = (const int*)d_in[1];
    const int* src = edge_index;             // edge_index[0, :]
    const int* dst = edge_index + N_EDGES;   // edge_index[1, :]
    const float* W1 = (const float*)d_in[3];
    const float* b1 = (const float*)d_in[4];
    const float* W2 = (const float*)d_in[5];
    const float* b2 = (const float*)d_in[6];
    float* out = (float*)d_out;

    const size_t ND = (size_t)N_NODES * D;
    float* xw1     = (float*)d_ws;                 // 51.2 MB
    float* xw2     = xw1 + ND;                     // 1.2 MB
    float* dinv    = xw2 + (size_t)N_NODES * 3;    // 0.4 MB
    int*   cnt     = (int*)(dinv + N_NODES);       // 0.4 MB (count-down cursor in fill)
    int*   row_ptr = cnt + N_NODES;                // 0.4 MB
    int*   esrc    = row_ptr + (N_NODES + 1);      // 6.4 MB
    int*   bsum    = esrc + N_EDGES;               // 1.6 KB
    int*   boff    = bsum + NB_SCAN;               // 1.6 KB

    // CSR build (grouped by dst)
    hipMemsetAsync(cnt, 0, N_NODES * sizeof(int), stream);
    deg_kernel<<<(N_EDGES + 255) / 256, 256, 0, stream>>>(dst, cnt);
    dinv_kernel<<<(N_NODES + 255) / 256, 256, 0, stream>>>(cnt, dinv);
    scan1_kernel<<<NB_SCAN, 256, 0, stream>>>(cnt, bsum);
    scan2_kernel<<<1, 512, 0, stream>>>(bsum, boff, row_ptr);
    scan3_kernel<<<NB_SCAN, 256, 0, stream>>>(cnt, boff, row_ptr);
    fill_kernel<<<(N_EDGES + 255) / 256, 256, 0, stream>>>(src, dst, row_ptr, cnt, esrc);

    // layer 1 GEMM, then fused gather1+gemm2, then gather2
    gemm1_kernel<<<N_NODES / 16, 256, 0, stream>>>(feature, W1, xw1);
    gather1_kernel<<<N_NODES / 8, 256, 0, stream>>>(row_ptr, esrc, dinv, xw1, b1, W2, xw2);
    gather2_kernel<<<(N_NODES + 63) / 64, 256, 0, stream>>>(row_ptr, esrc, dinv, xw2, b2, out);
}

// Round 6
// 321.052 us; speedup vs baseline: 4.2736x; 1.3855x over previous
//
#include <hip/hip_runtime.h>

#define N_NODES 100000
#define N_EDGES 1600000
#define D 128
#define NBKT 391        // ceil(100000/256) buckets of 256 dst nodes
#define BKT_CAP 5120    // mean bucket size 4096, sigma~64 -> 16-sigma margin
#define NB_GEMM 3125    // 100000/32 rows
#define NB_BINA 782     // ceil((1600000/4) int4 / 512 threads)

// ==================== mega kernel: gemm1 blocks || binA blocks ====================
// gemm1: xw1 = feature @ W1 (W1 + 32 feature rows in LDS, 80KB -> 2 blocks/CU).
// binA : bin edges by dst>>8 into bucket regions; per-block LDS ranks + one
//        global atomicAdd per (block,bucket) -> clustered, L2-mergeable writes.

__global__ __launch_bounds__(512) void mega_kernel(const float* __restrict__ x,
                                                   const float* __restrict__ W,
                                                   float* __restrict__ xw,
                                                   const int* __restrict__ src,
                                                   const int* __restrict__ dst,
                                                   int* __restrict__ gcnt,
                                                   int* __restrict__ staged) {
    __shared__ __align__(16) char smem[81920];
    const int tid = threadIdx.x;
    const int bid = blockIdx.x;

    if (bid < NB_GEMM) {
        // ---- gemm1 path ----
        float* ws_ = (float*)smem;            // 128x128 = 64KB
        float* xs_ = (float*)smem + 16384;    // 32x128  = 16KB
        float4* ws4 = (float4*)ws_;
        const float4* W4 = (const float4*)W;
#pragma unroll
        for (int i = 0; i < 8; ++i) ws4[tid + i * 512] = W4[tid + i * 512];  // 4096 float4
        const int row0 = bid * 32;  // N_NODES % 32 == 0
        const float4* x4 = (const float4*)(x + (size_t)row0 * D);
        float4* xs4 = (float4*)xs_;
        xs4[tid] = x4[tid];
        xs4[tid + 512] = x4[tid + 512];
        __syncthreads();
        const int rg = tid >> 5;          // 0..15
        const int c0 = (tid & 31) * 4;
        float acc0[4] = {0, 0, 0, 0}, acc1[4] = {0, 0, 0, 0};
#pragma unroll 8
        for (int k = 0; k < D; ++k) {
            const float4 wv = *(const float4*)&ws_[k * D + c0];
            const float xv0 = xs_[rg * D + k];
            const float xv1 = xs_[(rg + 16) * D + k];
            acc0[0] += xv0 * wv.x; acc0[1] += xv0 * wv.y;
            acc0[2] += xv0 * wv.z; acc0[3] += xv0 * wv.w;
            acc1[0] += xv1 * wv.x; acc1[1] += xv1 * wv.y;
            acc1[2] += xv1 * wv.z; acc1[3] += xv1 * wv.w;
        }
        *(float4*)&xw[(size_t)(row0 + rg) * D + c0] = *(float4*)acc0;
        *(float4*)&xw[(size_t)(row0 + rg + 16) * D + c0] = *(float4*)acc1;
    } else {
        // ---- binA path ----
        int* hist = (int*)smem;  // [NBKT] local counts -> then block's global base
        if (tid < NBKT) hist[tid] = 0;
        __syncthreads();
        const int i4 = (bid - NB_GEMM) * 512 + tid;
        const bool valid = i4 < N_EDGES / 4;
        int4 dv, sv;
        int lb0 = 0, lb1 = 0, lb2 = 0, lb3 = 0, lr0 = 0, lr1 = 0, lr2 = 0, lr3 = 0;
        if (valid) {
            dv = ((const int4*)dst)[i4];
            sv = ((const int4*)src)[i4];
            lb0 = dv.x >> 8; lr0 = atomicAdd(&hist[lb0], 1);
            lb1 = dv.y >> 8; lr1 = atomicAdd(&hist[lb1], 1);
            lb2 = dv.z >> 8; lr2 = atomicAdd(&hist[lb2], 1);
            lb3 = dv.w >> 8; lr3 = atomicAdd(&hist[lb3], 1);
        }
        __syncthreads();
        if (tid < NBKT) {
            const int c = hist[tid];
            hist[tid] = c ? atomicAdd(&gcnt[tid], c) : 0;  // block's base within bucket
        }
        __syncthreads();
        if (valid) {
            // packed record: src (17 bits) << 8 | dst_local (8 bits)
            staged[lb0 * BKT_CAP + hist[lb0] + lr0] = (sv.x << 8) | (dv.x & 255);
            staged[lb1 * BKT_CAP + hist[lb1] + lr1] = (sv.y << 8) | (dv.y & 255);
            staged[lb2 * BKT_CAP + hist[lb2] + lr2] = (sv.z << 8) | (dv.z & 255);
            staged[lb3 * BKT_CAP + hist[lb3] + lr3] = (sv.w << 8) | (dv.w & 255);
        }
    }
}

// ==================== binB: per-bucket CSR emit (row_ptr, dinv, esrc) ====================
// One block per bucket. All esrc writes fall in the bucket's contiguous region.

__global__ __launch_bounds__(256) void binB_kernel(const int* __restrict__ gcnt,
                                                   const int* __restrict__ staged,
                                                   int* __restrict__ row_ptr,
                                                   int* __restrict__ esrc,
                                                   float* __restrict__ dinv) {
    __shared__ int red[256];
    __shared__ int hist[256];
    __shared__ int nbase[256];
    __shared__ int nexc[256];
    const int b = blockIdx.x;
    const int t = threadIdx.x;
    const int m = gcnt[b];
    // bucket global offset = exclusive prefix of gcnt up to b
    int partial = 0;
    for (int i = t; i < b; i += 256) partial += gcnt[i];
    red[t] = partial;
    __syncthreads();
    for (int off = 128; off; off >>= 1) {
        if (t < off) red[t] += red[t + off];
        __syncthreads();
    }
    const int bbase = red[0];
    // node-local degree histogram
    hist[t] = 0;
    __syncthreads();
    const int* reg = staged + (size_t)b * BKT_CAP;
    for (int i = t; i < m; i += 256) atomicAdd(&hist[reg[i] & 255], 1);
    __syncthreads();
    const int v = hist[t];
    nbase[t] = v;
    __syncthreads();
    for (int off = 1; off < 256; off <<= 1) {  // inclusive Hillis-Steele scan
        int u = (t >= off) ? nbase[t - off] : 0;
        __syncthreads();
        nbase[t] += u;
        __syncthreads();
    }
    nexc[t] = nbase[t] - v;  // exclusive
    const int node = b * 256 + t;
    if (node < N_NODES) {
        row_ptr[node] = bbase + nexc[t];
        dinv[node] = rsqrtf((float)v + 1.0f);  // +1 = self-loop
    }
    if (b == 0 && t == 0) row_ptr[N_NODES] = N_EDGES;
    hist[t] = 0;  // reuse as per-node cursor
    __syncthreads();
    for (int i = t; i < m; i += 256) {
        const int rec = reg[i];
        const int nl = rec & 255;
        const int r = atomicAdd(&hist[nl], 1);
        esrc[bbase + nexc[nl] + r] = rec >> 8;
    }
}

// ==================== layer 1 gather + fused layer 2 GEMM ====================
// 8 nodes per 256-thread block; 32 threads per node, float4 per thread.
// h stays in registers; multiplied by W2 and shuffle-reduced -> xw2.

__global__ __launch_bounds__(256) void gather1_kernel(const int* __restrict__ row_ptr,
                                                      const int* __restrict__ esrc,
                                                      const float* __restrict__ dinv,
                                                      const float* __restrict__ xw,
                                                      const float* __restrict__ b1,
                                                      const float* __restrict__ W2,
                                                      float* __restrict__ xw2) {
    const int t = threadIdx.x;
    const int n = blockIdx.x * 8 + (t >> 5);  // N_NODES % 8 == 0
    const int g = t & 31;                      // 4-channel group within the row
    const float4* xw4 = (const float4*)xw;
    const int beg = row_ptr[n], end = row_ptr[n + 1];
    float ax = 0.f, ay = 0.f, az = 0.f, aw = 0.f;
    int j = beg;
    for (; j + 1 < end; j += 2) {  // two independent 16B load chains
        const int s0 = esrc[j];
        const int s1 = esrc[j + 1];
        const float d0 = dinv[s0];
        const float d1 = dinv[s1];
        const float4 v0 = xw4[(size_t)s0 * 32 + g];
        const float4 v1 = xw4[(size_t)s1 * 32 + g];
        ax += v0.x * d0 + v1.x * d1;
        ay += v0.y * d0 + v1.y * d1;
        az += v0.z * d0 + v1.z * d1;
        aw += v0.w * d0 + v1.w * d1;
    }
    if (j < end) {
        const int s = esrc[j];
        const float ds = dinv[s];
        const float4 v = xw4[(size_t)s * 32 + g];
        ax += v.x * ds; ay += v.y * ds; az += v.z * ds; aw += v.w * ds;
    }
    const float dn = dinv[n];
    const float4 vn = xw4[(size_t)n * 32 + g];
    const float4 bb = ((const float4*)b1)[g];
    const float h0 = fmaxf((ax + vn.x * dn) * dn + bb.x, 0.f);
    const float h1 = fmaxf((ay + vn.y * dn) * dn + bb.y, 0.f);
    const float h2 = fmaxf((az + vn.z * dn) * dn + bb.z, 0.f);
    const float h3 = fmaxf((aw + vn.w * dn) * dn + bb.w, 0.f);
    // fused gemm2: channels c = 4g..4g+3; W2 is [128][3] (L1-resident)
    const int c = g * 4;
    float a0 = h0 * W2[c * 3 + 0] + h1 * W2[(c + 1) * 3 + 0] + h2 * W2[(c + 2) * 3 + 0] + h3 * W2[(c + 3) * 3 + 0];
    float a1 = h0 * W2[c * 3 + 1] + h1 * W2[(c + 1) * 3 + 1] + h2 * W2[(c + 2) * 3 + 1] + h3 * W2[(c + 3) * 3 + 1];
    float a2 = h0 * W2[c * 3 + 2] + h1 * W2[(c + 1) * 3 + 2] + h2 * W2[(c + 2) * 3 + 2] + h3 * W2[(c + 3) * 3 + 2];
#pragma unroll
    for (int off = 16; off; off >>= 1) {  // reduce within the 32-lane group
        a0 += __shfl_xor(a0, off);
        a1 += __shfl_xor(a1, off);
        a2 += __shfl_xor(a2, off);
    }
    if (g == 0) {
        xw2[n * 3 + 0] = a0;
        xw2[n * 3 + 1] = a1;
        xw2[n * 3 + 2] = a2;
    }
}

// ==================== layer 2 gather: 4 lanes per node ====================

__global__ __launch_bounds__(256) void gather2_kernel(const int* __restrict__ row_ptr,
                                                      const int* __restrict__ esrc,
                                                      const float* __restrict__ dinv,
                                                      const float* __restrict__ xw2,
                                                      const float* __restrict__ b2,
                                                      float* __restrict__ out) {
    const int t = threadIdx.x;
    const int node = blockIdx.x * 64 + (t >> 2);
    if (node >= N_NODES) return;
    const int sub = t & 3;
    const int beg = row_ptr[node], end = row_ptr[node + 1];
    float a0 = 0.f, a1 = 0.f, a2 = 0.f;
    for (int j = beg + sub; j < end; j += 4) {
        const int s = esrc[j];
        const float ds = dinv[s];
        a0 += xw2[s * 3 + 0] * ds;
        a1 += xw2[s * 3 + 1] * ds;
        a2 += xw2[s * 3 + 2] * ds;
    }
    a0 += __shfl_xor(a0, 1); a0 += __shfl_xor(a0, 2);
    a1 += __shfl_xor(a1, 1); a1 += __shfl_xor(a1, 2);
    a2 += __shfl_xor(a2, 1); a2 += __shfl_xor(a2, 2);
    if (sub == 0) {
        const float dn = dinv[node];
        out[node * 3 + 0] = (a0 + xw2[node * 3 + 0] * dn) * dn + b2[0];
        out[node * 3 + 1] = (a1 + xw2[node * 3 + 1] * dn) * dn + b2[1];
        out[node * 3 + 2] = (a2 + xw2[node * 3 + 2] * dn) * dn + b2[2];
    }
}

// ==================== launch ====================

extern "C" void kernel_launch(void* const* d_in, const int* in_sizes, int n_in,
                              void* d_out, int out_size, void* d_ws, size_t ws_size,
                              hipStream_t stream) {
    const float* feature = (const float*)d_in[0];
    const int* edge_index = (const int*)d_in[1];
    const int* src = edge_index;             // edge_index[0, :]
    const int* dst = edge_index + N_EDGES;   // edge_index[1, :]
    const float* W1 = (const float*)d_in[3];
    const float* b1 = (const float*)d_in[4];
    const float* W2 = (const float*)d_in[5];
    const float* b2 = (const float*)d_in[6];
    float* out = (float*)d_out;

    const size_t ND = (size_t)N_NODES * D;
    float* xw1     = (float*)d_ws;                   // 51.2 MB
    float* xw2     = xw1 + ND;                       // 1.2 MB
    float* dinv    = xw2 + (size_t)N_NODES * 3;      // 0.4 MB
    int*   row_ptr = (int*)(dinv + N_NODES);         // 0.4 MB
    int*   esrc    = row_ptr + (N_NODES + 1);        // 6.4 MB
    int*   gcnt    = esrc + N_EDGES;                 // 1.6 KB
    int*   staged  = gcnt + NBKT;                    // 8.0 MB (NBKT*BKT_CAP)

    hipMemsetAsync(gcnt, 0, NBKT * sizeof(int), stream);
    mega_kernel<<<NB_GEMM + NB_BINA, 512, 0, stream>>>(feature, W1, xw1, src, dst, gcnt, staged);
    binB_kernel<<<NBKT, 256, 0, stream>>>(gcnt, staged, row_ptr, esrc, dinv);
    gather1_kernel<<<N_NODES / 8, 256, 0, stream>>>(row_ptr, esrc, dinv, xw1, b1, W2, xw2);
    gather2_kernel<<<(N_NODES + 63) / 64, 256, 0, stream>>>(row_ptr, esrc, dinv, xw2, b2, out);
}

// Round 7
// 268.724 us; speedup vs baseline: 5.1058x; 1.1947x over previous
//
#include <hip/hip_runtime.h>
#include <hip/hip_fp16.h>

#define N_NODES 100000
#define N_EDGES 1600000
#define D 128
#define NBKT 391        // ceil(100000/256) buckets of 256 dst nodes
#define BKT_CAP 5120    // mean bucket size 4096, sigma~64 -> 16-sigma margin
#define NB_GEMM 3125    // 100000/32 rows
#define NB_BINA 782     // ceil((1600000/4) int4 / 512 threads)

// ==================== mega kernel: gemm1 blocks || binA blocks ====================

__global__ __launch_bounds__(512) void mega_kernel(const float* __restrict__ x,
                                                   const float* __restrict__ W,
                                                   float* __restrict__ xw,
                                                   const int* __restrict__ src,
                                                   const int* __restrict__ dst,
                                                   int* __restrict__ gcnt,
                                                   int* __restrict__ staged) {
    __shared__ __align__(16) char smem[81920];
    const int tid = threadIdx.x;
    const int bid = blockIdx.x;

    if (bid < NB_GEMM) {
        // ---- gemm1: xw1 = feature @ W1 (W1 + 32 rows in LDS, 80KB -> 2 blocks/CU) ----
        float* ws_ = (float*)smem;            // 128x128 = 64KB
        float* xs_ = (float*)smem + 16384;    // 32x128  = 16KB
        float4* ws4 = (float4*)ws_;
        const float4* W4 = (const float4*)W;
#pragma unroll
        for (int i = 0; i < 8; ++i) ws4[tid + i * 512] = W4[tid + i * 512];
        const int row0 = bid * 32;  // N_NODES % 32 == 0
        const float4* x4 = (const float4*)(x + (size_t)row0 * D);
        float4* xs4 = (float4*)xs_;
        xs4[tid] = x4[tid];
        xs4[tid + 512] = x4[tid + 512];
        __syncthreads();
        const int rg = tid >> 5;          // 0..15
        const int c0 = (tid & 31) * 4;
        float acc0[4] = {0, 0, 0, 0}, acc1[4] = {0, 0, 0, 0};
#pragma unroll 8
        for (int k = 0; k < D; ++k) {
            const float4 wv = *(const float4*)&ws_[k * D + c0];
            const float xv0 = xs_[rg * D + k];
            const float xv1 = xs_[(rg + 16) * D + k];
            acc0[0] += xv0 * wv.x; acc0[1] += xv0 * wv.y;
            acc0[2] += xv0 * wv.z; acc0[3] += xv0 * wv.w;
            acc1[0] += xv1 * wv.x; acc1[1] += xv1 * wv.y;
            acc1[2] += xv1 * wv.z; acc1[3] += xv1 * wv.w;
        }
        *(float4*)&xw[(size_t)(row0 + rg) * D + c0] = *(float4*)acc0;
        *(float4*)&xw[(size_t)(row0 + rg + 16) * D + c0] = *(float4*)acc1;
    } else {
        // ---- binA: bin edges by dst>>8; LDS ranks + one global atomicAdd per (block,bucket) ----
        int* hist = (int*)smem;
        if (tid < NBKT) hist[tid] = 0;
        __syncthreads();
        const int i4 = (bid - NB_GEMM) * 512 + tid;
        const bool valid = i4 < N_EDGES / 4;
        int4 dv, sv;
        int lb0 = 0, lb1 = 0, lb2 = 0, lb3 = 0, lr0 = 0, lr1 = 0, lr2 = 0, lr3 = 0;
        if (valid) {
            dv = ((const int4*)dst)[i4];
            sv = ((const int4*)src)[i4];
            lb0 = dv.x >> 8; lr0 = atomicAdd(&hist[lb0], 1);
            lb1 = dv.y >> 8; lr1 = atomicAdd(&hist[lb1], 1);
            lb2 = dv.z >> 8; lr2 = atomicAdd(&hist[lb2], 1);
            lb3 = dv.w >> 8; lr3 = atomicAdd(&hist[lb3], 1);
        }
        __syncthreads();
        if (tid < NBKT) {
            const int c = hist[tid];
            hist[tid] = c ? atomicAdd(&gcnt[tid], c) : 0;
        }
        __syncthreads();
        if (valid) {
            staged[lb0 * BKT_CAP + hist[lb0] + lr0] = (sv.x << 8) | (dv.x & 255);
            staged[lb1 * BKT_CAP + hist[lb1] + lr1] = (sv.y << 8) | (dv.y & 255);
            staged[lb2 * BKT_CAP + hist[lb2] + lr2] = (sv.z << 8) | (dv.z & 255);
            staged[lb3 * BKT_CAP + hist[lb3] + lr3] = (sv.w << 8) | (dv.w & 255);
        }
    }
}

// ==================== binB: per-bucket CSR emit (row_ptr, dinv, esrc) ====================

__global__ __launch_bounds__(256) void binB_kernel(const int* __restrict__ gcnt,
                                                   const int* __restrict__ staged,
                                                   int* __restrict__ row_ptr,
                                                   int* __restrict__ esrc,
                                                   float* __restrict__ dinv) {
    __shared__ int red[256];
    __shared__ int hist[256];
    __shared__ int nbase[256];
    __shared__ int nexc[256];
    const int b = blockIdx.x;
    const int t = threadIdx.x;
    const int m = gcnt[b];
    int partial = 0;
    for (int i = t; i < b; i += 256) partial += gcnt[i];
    red[t] = partial;
    __syncthreads();
    for (int off = 128; off; off >>= 1) {
        if (t < off) red[t] += red[t + off];
        __syncthreads();
    }
    const int bbase = red[0];
    hist[t] = 0;
    __syncthreads();
    const int* reg = staged + (size_t)b * BKT_CAP;
    for (int i = t; i < m; i += 256) atomicAdd(&hist[reg[i] & 255], 1);
    __syncthreads();
    const int v = hist[t];
    nbase[t] = v;
    __syncthreads();
    for (int off = 1; off < 256; off <<= 1) {
        int u = (t >= off) ? nbase[t - off] : 0;
        __syncthreads();
        nbase[t] += u;
        __syncthreads();
    }
    nexc[t] = nbase[t] - v;
    const int node = b * 256 + t;
    if (node < N_NODES) {
        row_ptr[node] = bbase + nexc[t];
        dinv[node] = rsqrtf((float)v + 1.0f);  // +1 = self-loop
    }
    if (b == 0 && t == 0) row_ptr[N_NODES] = N_EDGES;
    hist[t] = 0;
    __syncthreads();
    for (int i = t; i < m; i += 256) {
        const int rec = reg[i];
        const int nl = rec & 255;
        const int r = atomicAdd(&hist[nl], 1);
        esrc[bbase + nexc[nl] + r] = rec >> 8;
    }
}

// ==================== qscale: q[n] = fp16(xw1[n] * dinv[n]) ====================
// Thread i: node n=i>>4, 8 channels at (i&15)*8. 32B read, 16B write, coalesced.

__global__ __launch_bounds__(256) void qscale_kernel(const float* __restrict__ xw,
                                                     const float* __restrict__ dinv,
                                                     uint4* __restrict__ q4) {
    const int i = blockIdx.x * blockDim.x + threadIdx.x;  // N_NODES*16 total, exact
    const int n = i >> 4;
    const float dn = dinv[n];
    const float4 a = *(const float4*)&xw[(size_t)i * 8];
    const float4 b = *(const float4*)&xw[(size_t)i * 8 + 4];
    union { uint4 u; __half h[8]; } o;
    o.h[0] = __float2half(a.x * dn); o.h[1] = __float2half(a.y * dn);
    o.h[2] = __float2half(a.z * dn); o.h[3] = __float2half(a.w * dn);
    o.h[4] = __float2half(b.x * dn); o.h[5] = __float2half(b.y * dn);
    o.h[6] = __float2half(b.z * dn); o.h[7] = __float2half(b.w * dn);
    q4[i] = o.u;
}

// ==================== gather1 + fused gemm2 ====================
// 16 nodes per 256-thread block; 16 lanes/node, half8 (16B) per lane.
// h = (sum_s q[s] + q[n]) * dinv_n + b1, relu, then y[n] = (h @ W2) * dinv_n.

__global__ __launch_bounds__(256) void gather1_kernel(const int* __restrict__ row_ptr,
                                                      const int* __restrict__ esrc,
                                                      const float* __restrict__ dinv,
                                                      const uint4* __restrict__ q4,
                                                      const float* __restrict__ b1,
                                                      const float* __restrict__ W2,
                                                      float* __restrict__ y) {
    const int t = threadIdx.x;
    const int n = blockIdx.x * 16 + (t >> 4);  // N_NODES % 16 == 0
    const int g = t & 15;                      // 8-channel group
    const int beg = row_ptr[n], end = row_ptr[n + 1];
    float acc[8] = {0, 0, 0, 0, 0, 0, 0, 0};
    union U { uint4 u; __half2 h2[4]; };
    int j = beg;
    for (; j + 1 < end; j += 2) {  // two independent 16B load chains
        const int s0 = esrc[j];
        const int s1 = esrc[j + 1];
        U u0, u1;
        u0.u = q4[(size_t)s0 * 16 + g];
        u1.u = q4[(size_t)s1 * 16 + g];
#pragma unroll
        for (int k = 0; k < 4; ++k) {
            const float2 f0 = __half22float2(u0.h2[k]);
            const float2 f1 = __half22float2(u1.h2[k]);
            acc[2 * k + 0] += f0.x + f1.x;
            acc[2 * k + 1] += f0.y + f1.y;
        }
    }
    if (j < end) {
        U u0; u0.u = q4[(size_t)esrc[j] * 16 + g];
#pragma unroll
        for (int k = 0; k < 4; ++k) {
            const float2 f0 = __half22float2(u0.h2[k]);
            acc[2 * k + 0] += f0.x;
            acc[2 * k + 1] += f0.y;
        }
    }
    // self-loop (q[n] already includes dinv[n]) + bias + relu
    const float dn = dinv[n];
    U un; un.u = q4[(size_t)n * 16 + g];
    const float4 ba = ((const float4*)b1)[g * 2];
    const float4 bb = ((const float4*)b1)[g * 2 + 1];
    float h[8];
#pragma unroll
    for (int k = 0; k < 4; ++k) {
        const float2 fn = __half22float2(un.h2[k]);
        h[2 * k + 0] = acc[2 * k + 0] + fn.x;
        h[2 * k + 1] = acc[2 * k + 1] + fn.y;
    }
    h[0] = fmaxf(h[0] * dn + ba.x, 0.f); h[1] = fmaxf(h[1] * dn + ba.y, 0.f);
    h[2] = fmaxf(h[2] * dn + ba.z, 0.f); h[3] = fmaxf(h[3] * dn + ba.w, 0.f);
    h[4] = fmaxf(h[4] * dn + bb.x, 0.f); h[5] = fmaxf(h[5] * dn + bb.y, 0.f);
    h[6] = fmaxf(h[6] * dn + bb.z, 0.f); h[7] = fmaxf(h[7] * dn + bb.w, 0.f);
    // fused gemm2 over this lane's channels c = 8g..8g+7
    const int c = g * 8;
    float a0 = 0.f, a1 = 0.f, a2 = 0.f;
#pragma unroll
    for (int k = 0; k < 8; ++k) {
        a0 += h[k] * W2[(c + k) * 3 + 0];
        a1 += h[k] * W2[(c + k) * 3 + 1];
        a2 += h[k] * W2[(c + k) * 3 + 2];
    }
#pragma unroll
    for (int off = 8; off; off >>= 1) {  // reduce across the 16-lane group
        a0 += __shfl_xor(a0, off);
        a1 += __shfl_xor(a1, off);
        a2 += __shfl_xor(a2, off);
    }
    if (g == 0) {  // store y[n] = xw2[n] * dinv[n]
        y[n * 3 + 0] = a0 * dn;
        y[n * 3 + 1] = a1 * dn;
        y[n * 3 + 2] = a2 * dn;
    }
}

// ==================== gather2: out = (sum_s y_s + y_n) * dinv_n + b2 ====================

__global__ __launch_bounds__(256) void gather2_kernel(const int* __restrict__ row_ptr,
                                                      const int* __restrict__ esrc,
                                                      const float* __restrict__ dinv,
                                                      const float* __restrict__ y,
                                                      const float* __restrict__ b2,
                                                      float* __restrict__ out) {
    const int t = threadIdx.x;
    const int node = blockIdx.x * 64 + (t >> 2);
    if (node >= N_NODES) return;
    const int sub = t & 3;
    const int beg = row_ptr[node], end = row_ptr[node + 1];
    float a0 = 0.f, a1 = 0.f, a2 = 0.f;
    for (int j = beg + sub; j < end; j += 4) {
        const int s = esrc[j];
        a0 += y[s * 3 + 0];
        a1 += y[s * 3 + 1];
        a2 += y[s * 3 + 2];
    }
    a0 += __shfl_xor(a0, 1); a0 += __shfl_xor(a0, 2);
    a1 += __shfl_xor(a1, 1); a1 += __shfl_xor(a1, 2);
    a2 += __shfl_xor(a2, 1); a2 += __shfl_xor(a2, 2);
    if (sub == 0) {
        const float dn = dinv[node];
        out[node * 3 + 0] = (a0 + y[node * 3 + 0]) * dn + b2[0];
        out[node * 3 + 1] = (a1 + y[node * 3 + 1]) * dn + b2[1];
        out[node * 3 + 2] = (a2 + y[node * 3 + 2]) * dn + b2[2];
    }
}

// ==================== launch ====================

extern "C" void kernel_launch(void* const* d_in, const int* in_sizes, int n_in,
                              void* d_out, int out_size, void* d_ws, size_t ws_size,
                              hipStream_t stream) {
    const float* feature = (const float*)d_in[0];
    const int* edge_index = (const int*)d_in[1];
    const int* src = edge_index;             // edge_index[0, :]
    const int* dst = edge_index + N_EDGES;   // edge_index[1, :]
    const float* W1 = (const float*)d_in[3];
    const float* b1 = (const float*)d_in[4];
    const float* W2 = (const float*)d_in[5];
    const float* b2 = (const float*)d_in[6];
    float* out = (float*)d_out;

    const size_t ND = (size_t)N_NODES * D;
    float* xw1     = (float*)d_ws;                   // 51.2 MB fp32
    uint4* q4      = (uint4*)(xw1 + ND);             // 25.6 MB fp16 (N*D*2B)
    float* y       = (float*)(q4 + (size_t)N_NODES * 16);  // 1.2 MB
    float* dinv    = y + (size_t)N_NODES * 3;        // 0.4 MB
    int*   row_ptr = (int*)(dinv + N_NODES);         // 0.4 MB
    int*   esrc    = row_ptr + (N_NODES + 1);        // 6.4 MB
    int*   gcnt    = esrc + N_EDGES;                 // 1.6 KB
    int*   staged  = gcnt + NBKT;                    // 8.0 MB

    hipMemsetAsync(gcnt, 0, NBKT * sizeof(int), stream);
    mega_kernel<<<NB_GEMM + NB_BINA, 512, 0, stream>>>(feature, W1, xw1, src, dst, gcnt, staged);
    binB_kernel<<<NBKT, 256, 0, stream>>>(gcnt, staged, row_ptr, esrc, dinv);
    qscale_kernel<<<N_NODES * 16 / 256, 256, 0, stream>>>(xw1, dinv, q4);
    gather1_kernel<<<N_NODES / 16, 256, 0, stream>>>(row_ptr, esrc, dinv, q4, b1, W2, y);
    gather2_kernel<<<(N_NODES + 63) / 64, 256, 0, stream>>>(row_ptr, esrc, dinv, y, b2, out);
}

// Round 9
// 222.106 us; speedup vs baseline: 6.1774x; 1.2099x over previous
//
#include <hip/hip_runtime.h>
#include <hip/hip_fp16.h>

#define N_NODES 100000
#define N_EDGES 1600000
#define D 128
#define NBKT 391        // ceil(100000/256) buckets of 256 dst nodes
#define BKT_CAP 5120    // mean bucket size 4096, sigma~64 -> 16-sigma margin
#define NB_GEMM 782     // ceil(100000/128) 128-row MFMA blocks
#define NB_BINA 782     // ceil((1600000/4)/512) edge-quad blocks

typedef _Float16 f16x8 __attribute__((ext_vector_type(8)));
typedef float f32x4 __attribute__((ext_vector_type(4)));

// XOR-swizzle for 256B-row-stride LDS tiles: flips byte bits 4..6 by (row&7).
// Applied identically on write and read (bijective within each row) -> b128
// column reads across 16 rows spread over 8 bank groups (2-way = free).
#define SWZ(b) ((b) ^ ((((b) >> 8) & 7) << 4))

// ==================== mega kernel: MFMA gemm1 blocks || binA blocks ====================
// gemm1: q = fp16(feature @ W1), unscaled. 512 thr = 8 waves x 16 rows = 128 rows/block.
// binA : bin edges by dst>>8 into bucket regions (unchanged).

__global__ __launch_bounds__(512) void mega_kernel(const float* __restrict__ x,
                                                   const float* __restrict__ W,
                                                   _Float16* __restrict__ q,
                                                   const int* __restrict__ src,
                                                   const int* __restrict__ dst,
                                                   int* __restrict__ gcnt,
                                                   int* __restrict__ staged) {
    __shared__ __align__(16) char smem[32768];
    const int tid = threadIdx.x;
    const int bid = blockIdx.x;

    if (bid < NB_GEMM) {
        // ---- MFMA gemm1 path ----
        const int lane = tid & 63;
        const int w = tid >> 6;        // wave 0..7 -> 16-row strip
        const int r16 = lane & 15;     // A-row / B-col / D-col within tile
        const int g = lane >> 4;       // k-group: k = g*8 + j
        const int row0 = bid * 128;
        const int row = row0 + w * 16 + r16;
        const int rowc = row < N_NODES ? row : N_NODES - 1;  // clamp loads, guard stores
        // A-frags direct from global: A[r16][kt*32 + g*8 + j], fp32 -> fp16
        const float* xp = x + (size_t)rowc * D;
        f16x8 a[4];
#pragma unroll
        for (int kt = 0; kt < 4; ++kt) {
            const float4 lo = *(const float4*)(xp + kt * 32 + g * 8);
            const float4 hi = *(const float4*)(xp + kt * 32 + g * 8 + 4);
            f16x8 v;
            v[0] = (_Float16)lo.x; v[1] = (_Float16)lo.y; v[2] = (_Float16)lo.z; v[3] = (_Float16)lo.w;
            v[4] = (_Float16)hi.x; v[5] = (_Float16)hi.y; v[6] = (_Float16)hi.z; v[7] = (_Float16)hi.w;
            a[kt] = v;
        }
        // Wt into LDS: fp16, transposed (Wt[n][k]), swizzled. Thread -> col n, 32 k's.
        {
            const int n = tid & 127;
            const int k0 = (tid >> 7) * 32;
#pragma unroll
            for (int c = 0; c < 4; ++c) {
                f16x8 v;
#pragma unroll
                for (int j = 0; j < 8; ++j) v[j] = (_Float16)W[(k0 + c * 8 + j) * D + n];
                const int byte = n * 256 + (k0 + c * 8) * 2;
                *(f16x8*)(smem + SWZ(byte)) = v;
            }
        }
        __syncthreads();
        // 8 col-tiles x 4 k-tiles of mfma_f32_16x16x32_f16
        f32x4 acc[8];
#pragma unroll
        for (int nt = 0; nt < 8; ++nt) {
            f32x4 c = {0.f, 0.f, 0.f, 0.f};
#pragma unroll
            for (int kt = 0; kt < 4; ++kt) {
                const int byte = (nt * 16 + r16) * 256 + kt * 64 + g * 16;
                const f16x8 b = *(const f16x8*)(smem + SWZ(byte));
                c = __builtin_amdgcn_mfma_f32_16x16x32_f16(a[kt], b, c, 0, 0, 0);
            }
            acc[nt] = c;
        }
        __syncthreads();  // all waves done reading Wt -> reuse smem as q staging
        // D mapping (m89-verified): D[(lane>>4)*4 + r][lane&15]
        _Float16* qs = (_Float16*)smem;  // [128 rows][128 cols] linear
#pragma unroll
        for (int nt = 0; nt < 8; ++nt)
#pragma unroll
            for (int r = 0; r < 4; ++r)
                qs[(w * 16 + g * 4 + r) * D + nt * 16 + r16] = (_Float16)acc[nt][r];
        __syncthreads();
        // cooperative coalesced b128 write of the block's 128 q rows
        uint4* qg = (uint4*)q;
#pragma unroll
        for (int i = 0; i < 4; ++i) {
            const int c16 = tid + i * 512;       // 16B chunk; 16 chunks per row
            const int grow = row0 + (c16 >> 4);
            if (grow < N_NODES)
                qg[(size_t)grow * 16 + (c16 & 15)] = *(const uint4*)(smem + c16 * 16);
        }
    } else {
        // ---- binA path: LDS ranks + one global atomicAdd per (block,bucket) ----
        int* hist = (int*)smem;
        if (tid < NBKT) hist[tid] = 0;
        __syncthreads();
        const int i4 = (bid - NB_GEMM) * 512 + tid;
        const bool valid = i4 < N_EDGES / 4;
        int4 dv, sv;
        int lb0 = 0, lb1 = 0, lb2 = 0, lb3 = 0, lr0 = 0, lr1 = 0, lr2 = 0, lr3 = 0;
        if (valid) {
            dv = ((const int4*)dst)[i4];
            sv = ((const int4*)src)[i4];
            lb0 = dv.x >> 8; lr0 = atomicAdd(&hist[lb0], 1);
            lb1 = dv.y >> 8; lr1 = atomicAdd(&hist[lb1], 1);
            lb2 = dv.z >> 8; lr2 = atomicAdd(&hist[lb2], 1);
            lb3 = dv.w >> 8; lr3 = atomicAdd(&hist[lb3], 1);
        }
        __syncthreads();
        if (tid < NBKT) {
            const int c = hist[tid];
            hist[tid] = c ? atomicAdd(&gcnt[tid], c) : 0;
        }
        __syncthreads();
        if (valid) {
            staged[lb0 * BKT_CAP + hist[lb0] + lr0] = (sv.x << 8) | (dv.x & 255);
            staged[lb1 * BKT_CAP + hist[lb1] + lr1] = (sv.y << 8) | (dv.y & 255);
            staged[lb2 * BKT_CAP + hist[lb2] + lr2] = (sv.z << 8) | (dv.z & 255);
            staged[lb3 * BKT_CAP + hist[lb3] + lr3] = (sv.w << 8) | (dv.w & 255);
        }
    }
}

// ==================== binB: per-bucket CSR emit (row_ptr, dinv, esrc) ====================

__global__ __launch_bounds__(256) void binB_kernel(const int* __restrict__ gcnt,
                                                   const int* __restrict__ staged,
                                                   int* __restrict__ row_ptr,
                                                   int* __restrict__ esrc,
                                                   float* __restrict__ dinv) {
    __shared__ int red[256];
    __shared__ int hist[256];
    __shared__ int nbase[256];
    __shared__ int nexc[256];
    const int b = blockIdx.x;
    const int t = threadIdx.x;
    const int m = gcnt[b];
    int partial = 0;
    for (int i = t; i < b; i += 256) partial += gcnt[i];
    red[t] = partial;
    __syncthreads();
    for (int off = 128; off; off >>= 1) {
        if (t < off) red[t] += red[t + off];
        __syncthreads();
    }
    const int bbase = red[0];
    hist[t] = 0;
    __syncthreads();
    const int* reg = staged + (size_t)b * BKT_CAP;
    for (int i = t; i < m; i += 256) atomicAdd(&hist[reg[i] & 255], 1);
    __syncthreads();
    const int v = hist[t];
    nbase[t] = v;
    __syncthreads();
    for (int off = 1; off < 256; off <<= 1) {
        int u = (t >= off) ? nbase[t - off] : 0;
        __syncthreads();
        nbase[t] += u;
        __syncthreads();
    }
    nexc[t] = nbase[t] - v;
    const int node = b * 256 + t;
    if (node < N_NODES) {
        row_ptr[node] = bbase + nexc[t];
        dinv[node] = rsqrtf((float)v + 1.0f);  // +1 = self-loop
    }
    if (b == 0 && t == 0) row_ptr[N_NODES] = N_EDGES;
    hist[t] = 0;
    __syncthreads();
    for (int i = t; i < m; i += 256) {
        const int rec = reg[i];
        const int nl = rec & 255;
        const int r = atomicAdd(&hist[nl], 1);
        esrc[bbase + nexc[nl] + r] = rec >> 8;
    }
}

// ==================== gather1 + fused gemm2 ====================
// 16 nodes per 256-thread block; 16 lanes/node, half8 (16B) per lane.
// h = (sum_s q[s]*dinv[s] + q[n]*dinv[n]) * dinv[n] + b1, relu; y[n] = (h @ W2) * dinv[n].

__global__ __launch_bounds__(256) void gather1_kernel(const int* __restrict__ row_ptr,
                                                      const int* __restrict__ esrc,
                                                      const float* __restrict__ dinv,
                                                      const uint4* __restrict__ q4,
                                                      const float* __restrict__ b1,
                                                      const float* __restrict__ W2,
                                                      float* __restrict__ y) {
    const int t = threadIdx.x;
    const int n = blockIdx.x * 16 + (t >> 4);  // N_NODES % 16 == 0
    const int g = t & 15;                      // 8-channel group
    const int beg = row_ptr[n], end = row_ptr[n + 1];
    float acc[8] = {0, 0, 0, 0, 0, 0, 0, 0};
    union U { uint4 u; __half2 h2[4]; };
    int j = beg;
    for (; j + 1 < end; j += 2) {  // two independent 16B load chains
        const int s0 = esrc[j];
        const int s1 = esrc[j + 1];
        const float d0 = dinv[s0];
        const float d1 = dinv[s1];
        U u0, u1;
        u0.u = q4[(size_t)s0 * 16 + g];
        u1.u = q4[(size_t)s1 * 16 + g];
#pragma unroll
        for (int k = 0; k < 4; ++k) {
            const float2 f0 = __half22float2(u0.h2[k]);
            const float2 f1 = __half22float2(u1.h2[k]);
            acc[2 * k + 0] += f0.x * d0 + f1.x * d1;
            acc[2 * k + 1] += f0.y * d0 + f1.y * d1;
        }
    }
    if (j < end) {
        const int s = esrc[j];
        const float ds = dinv[s];
        U u0; u0.u = q4[(size_t)s * 16 + g];
#pragma unroll
        for (int k = 0; k < 4; ++k) {
            const float2 f0 = __half22float2(u0.h2[k]);
            acc[2 * k + 0] += f0.x * ds;
            acc[2 * k + 1] += f0.y * ds;
        }
    }
    // self-loop + bias + relu
    const float dn = dinv[n];
    U un; un.u = q4[(size_t)n * 16 + g];
    const float4 ba = ((const float4*)b1)[g * 2];
    const float4 bb = ((const float4*)b1)[g * 2 + 1];
    float h[8];
#pragma unroll
    for (int k = 0; k < 4; ++k) {
        const float2 fn = __half22float2(un.h2[k]);
        h[2 * k + 0] = acc[2 * k + 0] + fn.x * dn;
        h[2 * k + 1] = acc[2 * k + 1] + fn.y * dn;
    }
    h[0] = fmaxf(h[0] * dn + ba.x, 0.f); h[1] = fmaxf(h[1] * dn + ba.y, 0.f);
    h[2] = fmaxf(h[2] * dn + ba.z, 0.f); h[3] = fmaxf(h[3] * dn + ba.w, 0.f);
    h[4] = fmaxf(h[4] * dn + bb.x, 0.f); h[5] = fmaxf(h[5] * dn + bb.y, 0.f);
    h[6] = fmaxf(h[6] * dn + bb.z, 0.f); h[7] = fmaxf(h[7] * dn + bb.w, 0.f);
    // fused gemm2 over this lane's channels c = 8g..8g+7
    const int c = g * 8;
    float a0 = 0.f, a1 = 0.f, a2 = 0.f;
#pragma unroll
    for (int k = 0; k < 8; ++k) {
        a0 += h[k] * W2[(c + k) * 3 + 0];
        a1 += h[k] * W2[(c + k) * 3 + 1];
        a2 += h[k] * W2[(c + k) * 3 + 2];
    }
#pragma unroll
    for (int off = 8; off; off >>= 1) {  // reduce across the 16-lane group
        a0 += __shfl_xor(a0, off);
        a1 += __shfl_xor(a1, off);
        a2 += __shfl_xor(a2, off);
    }
    if (g == 0) {  // store y[n] = xw2[n] * dinv[n]
        y[n * 3 + 0] = a0 * dn;
        y[n * 3 + 1] = a1 * dn;
        y[n * 3 + 2] = a2 * dn;
    }
}

// ==================== gather2: out = (sum_s y_s + y_n) * dinv_n + b2 ====================

__global__ __launch_bounds__(256) void gather2_kernel(const int* __restrict__ row_ptr,
                                                      const int* __restrict__ esrc,
                                                      const float* __restrict__ dinv,
                                                      const float* __restrict__ y,
                                                      const float* __restrict__ b2,
                                                      float* __restrict__ out) {
    const int t = threadIdx.x;
    const int node = blockIdx.x * 64 + (t >> 2);
    if (node >= N_NODES) return;
    const int sub = t & 3;
    const int beg = row_ptr[node], end = row_ptr[node + 1];
    float a0 = 0.f, a1 = 0.f, a2 = 0.f;
    for (int j = beg + sub; j < end; j += 4) {
        const int s = esrc[j];
        a0 += y[s * 3 + 0];
        a1 += y[s * 3 + 1];
        a2 += y[s * 3 + 2];
    }
    a0 += __shfl_xor(a0, 1); a0 += __shfl_xor(a0, 2);
    a1 += __shfl_xor(a1, 1); a1 += __shfl_xor(a1, 2);
    a2 += __shfl_xor(a2, 1); a2 += __shfl_xor(a2, 2);
    if (sub == 0) {
        const float dn = dinv[node];
        out[node * 3 + 0] = (a0 + y[node * 3 + 0]) * dn + b2[0];
        out[node * 3 + 1] = (a1 + y[node * 3 + 1]) * dn + b2[1];
        out[node * 3 + 2] = (a2 + y[node * 3 + 2]) * dn + b2[2];
    }
}

// ==================== launch ====================

extern "C" void kernel_launch(void* const* d_in, const int* in_sizes, int n_in,
                              void* d_out, int out_size, void* d_ws, size_t ws_size,
                              hipStream_t stream) {
    const float* feature = (const float*)d_in[0];
    const int* edge_index = (const int*)d_in[1];
    const int* src = edge_index;             // edge_index[0, :]
    const int* dst = edge_index + N_EDGES;   // edge_index[1, :]
    const float* W1 = (const float*)d_in[3];
    const float* b1 = (const float*)d_in[4];
    const float* W2 = (const float*)d_in[5];
    const float* b2 = (const float*)d_in[6];
    float* out = (float*)d_out;

    const size_t ND = (size_t)N_NODES * D;
    _Float16* q    = (_Float16*)d_ws;                // 25.6 MB fp16, unscaled xw1
    float* y       = (float*)(q + ND);               // 1.2 MB
    float* dinv    = y + (size_t)N_NODES * 3;        // 0.4 MB
    int*   row_ptr = (int*)(dinv + N_NODES);         // 0.4 MB
    int*   esrc    = row_ptr + (N_NODES + 1);        // 6.4 MB
    int*   gcnt    = esrc + N_EDGES;                 // 1.6 KB
    int*   staged  = gcnt + NBKT;                    // 8.0 MB

    hipMemsetAsync(gcnt, 0, NBKT * sizeof(int), stream);
    mega_kernel<<<NB_GEMM + NB_BINA, 512, 0, stream>>>(feature, W1, q, src, dst, gcnt, staged);
    binB_kernel<<<NBKT, 256, 0, stream>>>(gcnt, staged, row_ptr, esrc, dinv);
    gather1_kernel<<<N_NODES / 16, 256, 0, stream>>>(row_ptr, esrc, dinv, (const uint4*)q, b1, W2, y);
    gather2_kernel<<<(N_NODES + 63) / 64, 256, 0, stream>>>(row_ptr, esrc, dinv, y, b2, out);
}